// Round 6
// baseline (142.833 us; speedup 1.0000x reference)
//
#include <hip/hip_runtime.h>
#include <hip/hip_fp16.h>
#include <math.h>

#define SS 2048
#define DD 512
#define NH 8
#define HD 64

typedef __attribute__((ext_vector_type(8))) short frag_ab;   // 8 fp16
typedef __attribute__((ext_vector_type(4))) float frag_cd;   // 4 fp32

static __device__ inline unsigned int pack_h2(float x, float y) {
    __half2 t = __floats2half2_rn(x, y);   // x -> low half
    return *(unsigned int*)&t;
}

// ---------- wt[n][k] = fp16(Wq[k][n]) : 512x512 pre-transpose ----------
__global__ __launch_bounds__(256) void wt_kernel(const float* __restrict__ w,
                                                 unsigned short* __restrict__ wt) {
    __shared__ float T[64][69];
    const int tid = threadIdx.x;
    const int tk = blockIdx.x, tn = blockIdx.y;
    #pragma unroll
    for (int p = 0; p < 4; ++p) {
        const int r = (tid >> 4) + p * 16;
        const int c4 = (tid & 15) * 4;
        float4 v = *(const float4*)(w + (size_t)(tk * 64 + r) * 512 + tn * 64 + c4);
        T[r][c4] = v.x; T[r][c4 + 1] = v.y; T[r][c4 + 2] = v.z; T[r][c4 + 3] = v.w;
    }
    __syncthreads();
    #pragma unroll
    for (int p = 0; p < 2; ++p) {
        const int rn = (tid >> 3) + p * 32;
        const int ck = (tid & 7) * 8;
        unsigned int o[4];
        #pragma unroll
        for (int j = 0; j < 4; ++j)
            o[j] = pack_h2(T[ck + 2 * j][rn], T[ck + 2 * j + 1][rn]);
        *(uint4*)(wt + (size_t)(tn * 64 + rn) * 512 + tk * 64 + ck) = *(uint4*)o;
    }
}

// ---------- GEMM: q_h = fp16(x @ Wq). M64 x N64 tiles, dbuf A-LDS, B direct from wt ----------
__global__ __launch_bounds__(256, 4) void gemm_kernel(const float* __restrict__ x,
                                                      const unsigned short* __restrict__ wt,
                                                      unsigned short* __restrict__ q) {
    __shared__ __align__(16) unsigned short Ah[2][64 * 72];
    const int tid = threadIdx.x;
    const int lane = tid & 63, wv = tid >> 6;
    const int a = lane & 15, g = lane >> 4;
    const int bm = blockIdx.x, bn = blockIdx.y;

    frag_cd acc[4] = {};              // wave covers n-slice wv*16, all 64 m
    const int sr  = tid >> 4;
    const int sc4 = (tid & 15) * 4;

    float4 v[4];
    #pragma unroll
    for (int p = 0; p < 4; ++p)
        v[p] = *(const float4*)(x + (size_t)(bm * 64 + sr + p * 16) * 512 + sc4);

    const unsigned short* wp = wt + (size_t)(bn * 64 + wv * 16 + a) * 512 + g * 8;

    for (int it = 0; it < 8; ++it) {
        const int cur = it & 1;
        #pragma unroll
        for (int p = 0; p < 4; ++p) {
            uint2 hh = { pack_h2(v[p].x, v[p].y), pack_h2(v[p].z, v[p].w) };
            *(uint2*)&Ah[cur][(sr + p * 16) * 72 + sc4] = hh;
        }
        __syncthreads();
        if (it < 7) {                 // prefetch next A-tile (latency overlaps MFMAs)
            #pragma unroll
            for (int p = 0; p < 4; ++p)
                v[p] = *(const float4*)(x + (size_t)(bm * 64 + sr + p * 16) * 512 + (it + 1) * 64 + sc4);
        }
        #pragma unroll
        for (int kh = 0; kh < 2; ++kh) {
            const frag_ab bf = *(const frag_ab*)(wp + it * 64 + kh * 32);
            #pragma unroll
            for (int mt = 0; mt < 4; ++mt) {
                const frag_ab af = *(const frag_ab*)&Ah[cur][(mt * 16 + a) * 72 + kh * 32 + g * 8];
                acc[mt] = __builtin_amdgcn_mfma_f32_16x16x32_f16(af, bf, acc[mt], 0, 0, 0);
            }
        }
    }
    #pragma unroll
    for (int mt = 0; mt < 4; ++mt)
        #pragma unroll
        for (int r = 0; r < 4; ++r) {
            const int m = bm * 64 + mt * 16 + g * 4 + r;
            const int n = bn * 64 + wv * 16 + a;
            __half hv = __float2half_rn(acc[mt][r]);
            q[(size_t)m * 512 + n] = *(unsigned short*)&hv;
        }
}

// ---------- stage one 64-key K/V tile (natural layout) ----------
static __device__ inline void stage_kv(unsigned short* Kb, unsigned short* Vb,
                                       const unsigned int* d, int r0, int f0) {
    #pragma unroll
    for (int k = 0; k < 8; ++k)
        *(unsigned int*)&Kb[(r0 + k) * 72 + f0] = d[k];
    unsigned int vlo[4], vhi[4];
    #pragma unroll
    for (int j = 0; j < 4; ++j) {
        vlo[j] = (d[2 * j] & 0xFFFFu) | (d[2 * j + 1] << 16);
        vhi[j] = (d[2 * j] >> 16)     | (d[2 * j + 1] & 0xFFFF0000u);
    }
    *(uint4*)&Vb[f0 * 72 + r0]       = make_uint4(vlo[0], vlo[1], vlo[2], vlo[3]);
    *(uint4*)&Vb[(f0 + 1) * 72 + r0] = make_uint4(vhi[0], vhi[1], vhi[2], vhi[3]);
}

// ---------- Flash attention: f16 MFMA, 32 q/wave, key-split via gridDim.y ----------
// No-max softmax: p = e^(s-8); partial (O_unnorm, l) over a key range combines exactly:
// O = (O0+O1)/(l0+l1). gridDim.y==1 -> normalize+write out directly.
__global__ __launch_bounds__(256, 4) void attn_kernel(const __half* __restrict__ qg,
                                                      float* __restrict__ outp,
                                                      float* __restrict__ opart,
                                                      float* __restrict__ lpart) {
    __shared__ __align__(16) unsigned short Kt[64 * 72];      // [key][f]
    __shared__ __align__(16) unsigned short Vt[64 * 72];      // [f][key]
    __shared__ __align__(16) unsigned short Pq[4][32 * 72];   // per-wave [q][key]

    const int tid = threadIdx.x;
    const int lane = tid & 63, wv = tid >> 6;
    const int a = lane & 15, g = lane >> 4;
    const int bid = blockIdx.x;       // 512 = 16(qt) * 8(h) * 4(b)
    const int qt = bid & 15;
    const int h  = (bid >> 4) & 7;
    const int b  = bid >> 7;
    const int half = blockIdx.y;
    const int iters = 32 / gridDim.y;
    const int tb0 = half * iters;     // first 64-key tile index

    const unsigned short* qbh = (const unsigned short*)qg + (size_t)b * SS * DD + h * HD;
    const int qrow0 = qt * 128 + wv * 32;

    frag_ab qf[2][2];
    const __half2 qsc = __float2half2_rn(0.18033688011112042f);   // 0.125*log2(e)
    #pragma unroll
    for (int nt = 0; nt < 2; ++nt)
        #pragma unroll
        for (int kh = 0; kh < 2; ++kh) {
            frag_ab t = *(const frag_ab*)(qbh + (size_t)(qrow0 + nt * 16 + a) * DD + kh * 32 + g * 8);
            __half2* ph = (__half2*)&t;
            #pragma unroll
            for (int i = 0; i < 4; ++i) ph[i] = __hmul2(ph[i], qsc);
            qf[nt][kh] = t;
        }

    frag_cd oacc[4][2] = {};
    float lsum[2] = {0.f, 0.f};

    const int f0 = (tid & 31) * 2;
    const int r0 = (tid >> 5) * 8;
    unsigned short* myP = Pq[wv];

    unsigned int d[8];
    #pragma unroll
    for (int k = 0; k < 8; ++k)       // prologue: first tile -> regs
        d[k] = *(const unsigned int*)(qbh + (size_t)(tb0 * 64 + r0 + k) * DD + f0);

    for (int it = 0; it < iters; ++it) {
        __syncthreads();              // all waves done reading prev tile
        stage_kv(Kt, Vt, d, r0, f0);
        __syncthreads();              // staged tile visible

        if (it + 1 < iters) {         // prefetch next tile (overlaps compute)
            const int kb = (tb0 + it + 1) * 64;
            #pragma unroll
            for (int k = 0; k < 8; ++k)
                d[k] = *(const unsigned int*)(qbh + (size_t)(kb + r0 + k) * DD + f0);
        }

        // ---- S^T = K . Q^T ----
        frag_cd st[4][2];
        #pragma unroll
        for (int kt = 0; kt < 4; ++kt) {
            const frag_ab ka0 = *(const frag_ab*)&Kt[(kt * 16 + a) * 72 + g * 8];
            const frag_ab ka1 = *(const frag_ab*)&Kt[(kt * 16 + a) * 72 + 32 + g * 8];
            #pragma unroll
            for (int nt = 0; nt < 2; ++nt) {
                frag_cd c = {};
                c = __builtin_amdgcn_mfma_f32_16x16x32_f16(ka0, qf[nt][0], c, 0, 0, 0);
                c = __builtin_amdgcn_mfma_f32_16x16x32_f16(ka1, qf[nt][1], c, 0, 0, 0);
                st[kt][nt] = c;
            }
        }
        // ---- p = 2^(s' - 8*log2e), stage P ----
        #pragma unroll
        for (int nt = 0; nt < 2; ++nt) {
            const int prow = nt * 16 + a;
            #pragma unroll
            for (int kt = 0; kt < 4; ++kt) {
                const float p0 = __builtin_amdgcn_exp2f(st[kt][nt][0] - 11.541560327111707f);
                const float p1 = __builtin_amdgcn_exp2f(st[kt][nt][1] - 11.541560327111707f);
                const float p2 = __builtin_amdgcn_exp2f(st[kt][nt][2] - 11.541560327111707f);
                const float p3 = __builtin_amdgcn_exp2f(st[kt][nt][3] - 11.541560327111707f);
                lsum[nt] += (p0 + p1) + (p2 + p3);
                uint2 pw = { pack_h2(p0, p1), pack_h2(p2, p3) };
                *(uint2*)&myP[prow * 72 + kt * 16 + g * 4] = pw;
            }
        }
        // ---- O^T += V^T . P^T ----
        #pragma unroll
        for (int kh = 0; kh < 2; ++kh) {
            frag_ab va[4], pb[2];
            #pragma unroll
            for (int ft = 0; ft < 4; ++ft)
                va[ft] = *(const frag_ab*)&Vt[(ft * 16 + a) * 72 + kh * 32 + g * 8];
            #pragma unroll
            for (int nt = 0; nt < 2; ++nt)
                pb[nt] = *(const frag_ab*)&myP[(nt * 16 + a) * 72 + kh * 32 + g * 8];
            #pragma unroll
            for (int ft = 0; ft < 4; ++ft)
                #pragma unroll
                for (int nt = 0; nt < 2; ++nt)
                    oacc[ft][nt] = __builtin_amdgcn_mfma_f32_16x16x32_f16(va[ft], pb[nt], oacc[ft][nt], 0, 0, 0);
        }
    }

    #pragma unroll
    for (int nt = 0; nt < 2; ++nt) {
        float l = lsum[nt];
        l += __shfl_xor(l, 16, 64);
        l += __shfl_xor(l, 32, 64);
        const int qrow = qrow0 + nt * 16 + a;
        if (gridDim.y == 1) {
            const float inv = 1.f / l;
            float* op = outp + ((size_t)b * SS + qrow) * DD + h * HD;
            #pragma unroll
            for (int ft = 0; ft < 4; ++ft) {
                float4 vv = { oacc[ft][nt][0] * inv, oacc[ft][nt][1] * inv,
                              oacc[ft][nt][2] * inv, oacc[ft][nt][3] * inv };
                *(float4*)(op + ft * 16 + g * 4) = vv;
            }
        } else {
            float* op = opart + (size_t)half * 4194304u + ((size_t)b * SS + qrow) * DD + h * HD;
            #pragma unroll
            for (int ft = 0; ft < 4; ++ft) {
                float4 vv = { oacc[ft][nt][0], oacc[ft][nt][1],
                              oacc[ft][nt][2], oacc[ft][nt][3] };
                *(float4*)(op + ft * 16 + g * 4) = vv;
            }
            if (g == 0)
                lpart[half * 65536 + ((b << 3) + h) * 2048 + qrow] = l;
        }
    }
}

// ---------- combine: out = (O0 + O1) / (l0 + l1) ----------
__global__ __launch_bounds__(256) void combine_kernel(const float* __restrict__ opart,
                                                      const float* __restrict__ lpart,
                                                      float* __restrict__ out) {
    const int f4 = blockIdx.x * 256 + threadIdx.x;   // 0 .. 1048575
    const int dd = f4 * 4;
    const int b = dd >> 20;
    const int rem = dd & 1048575;
    const int qr = rem >> 9;
    const int h = (rem & 511) >> 6;
    const int li = ((b << 3) + h) * 2048 + qr;
    const float inv = 1.f / (lpart[li] + lpart[65536 + li]);
    const float4 o0 = *(const float4*)(opart + dd);
    const float4 o1 = *(const float4*)(opart + 4194304u + dd);
    float4 o = { (o0.x + o1.x) * inv, (o0.y + o1.y) * inv,
                 (o0.z + o1.z) * inv, (o0.w + o1.w) * inv };
    *(float4*)(out + dd) = o;
}

extern "C" void kernel_launch(void* const* d_in, const int* in_sizes, int n_in,
                              void* d_out, int out_size, void* d_ws, size_t ws_size,
                              hipStream_t stream) {
    const float* x  = (const float*)d_in[0];
    const float* wq = (const float*)d_in[1];
    float* out = (float*)d_out;

    char* ws = (char*)d_ws;
    unsigned short* q_h = (unsigned short*)ws;                 // 8 MB
    unsigned short* wt  = (unsigned short*)(ws + 8388608u);    // 512 KB
    float* opart = (float*)(ws + 8912896u);                    // 32 MB (2 halves)
    float* lpart = (float*)(ws + 42467328u);                   // 512 KB

    const bool split = (ws_size >= 42991616u);

    dim3 tgrid(8, 8);
    wt_kernel<<<tgrid, 256, 0, stream>>>(wq, wt);
    dim3 ggrid(128, 8);
    gemm_kernel<<<ggrid, 256, 0, stream>>>(x, wt, q_h);
    dim3 agrid(512, split ? 2 : 1);
    attn_kernel<<<agrid, 256, 0, stream>>>((const __half*)q_h, out, opart, lpart);
    if (split)
        combine_kernel<<<4096, 256, 0, stream>>>(opart, lpart, out);
}